// Round 10
// baseline (257.552 us; speedup 1.0000x reference)
//
#include <hip/hip_runtime.h>

// Sort_Latent_Layer: per row of (4096, 8192) fp32, view as 512 packets of 16,
// stable-argsort packets by first element, emit packets in sorted order.
//
// v8: two-dispatch split — decouple sort latency from memory streaming.
//  Kernel A: one wave per row (zero barriers), v5's verified in-wave bitonic
//    (8 elem/lane, DPP/ds_swizzle/shfl cross-lane). Writes u16 perm to d_ws.
//    Side effect: its stride-64B key loads pull the whole input into L3.
//  Kernel B: pure gather/stream. Per row: perm -> LDS, gather packets from
//    global (L3-hot), coalesced nontemporal stores. No sort in the path;
//    4096 blocks of pure memory work run near fill-kernel BW.
//  v7 lesson: compiler sank staged loads (VGPR stayed 12) -> sched_barrier(0)
//    between load and store phases in B.
//  Fallback: if ws_size < 4 MB, launch the v7 single-kernel path.

#define NPK 512       // packets per row
#define DIM 8192      // floats per row

typedef float vfloat4 __attribute__((ext_vector_type(4)));
typedef unsigned short vushort8 __attribute__((ext_vector_type(8)));

// ---------- shared helpers ----------

__device__ __forceinline__ unsigned long long shfl_xor_u64(unsigned long long v, int mask) {
    const int lo = __shfl_xor((int)(unsigned int)(v & 0xffffffffull), mask);
    const int hi = __shfl_xor((int)(unsigned int)(v >> 32), mask);
    return ((unsigned long long)(unsigned int)hi << 32) | (unsigned int)lo;
}

// xor-shuffle of 32 bits by lane-distance lj (compile-time constants only)
__device__ __forceinline__ unsigned int sx32(unsigned int x, int lj) {
    if (lj == 1)  return (unsigned int)__builtin_amdgcn_mov_dpp((int)x, 0xB1, 0xF, 0xF, true); // quad_perm [1,0,3,2]
    if (lj == 2)  return (unsigned int)__builtin_amdgcn_mov_dpp((int)x, 0x4E, 0xF, 0xF, true); // quad_perm [2,3,0,1]
    if (lj == 4)  return (unsigned int)__builtin_amdgcn_ds_swizzle((int)x, 0x101F);
    if (lj == 8)  return (unsigned int)__builtin_amdgcn_ds_swizzle((int)x, 0x201F);
    if (lj == 16) return (unsigned int)__builtin_amdgcn_ds_swizzle((int)x, 0x401F);
    return (unsigned int)__shfl_xor((int)x, lj);   // lj == 32
}

__device__ __forceinline__ unsigned long long sx64(unsigned long long v, int lj) {
    const unsigned int lo = sx32((unsigned int)v, lj);
    const unsigned int hi = sx32((unsigned int)(v >> 32), lj);
    return ((unsigned long long)hi << 32) | lo;
}

// ---------- Kernel A: per-wave argsort of 512 keys, perm -> workspace ----------

__global__ __launch_bounds__(256, 8)
void sort_keys_kernel(const float* __restrict__ z, unsigned short* __restrict__ perm) {
    const int t    = threadIdx.x;
    const int w    = t >> 6;                       // wave id = row within block
    const int lane = t & 63;
    const int row  = blockIdx.x * 4 + w;
    const float* __restrict__ zrow = z + (size_t)row * DIM;

    // Keys: element e = lane*8+s reads packet e's first float (warms L3).
    unsigned long long v[8];
#pragma unroll
    for (int s = 0; s < 8; ++s) {
        const int e = lane * 8 + s;
        unsigned int u = __float_as_uint(zrow[e * 16]);
        if (u == 0x80000000u) u = 0u;              // -0.0 -> +0.0 (tie)
        u = (u & 0x80000000u) ? ~u : (u | 0x80000000u);  // monotonic map
        v[s] = ((unsigned long long)u << 16) | (unsigned long long)e;
    }

    // Bitonic sort of 512 over (lane, slot), fully in-wave (v5 core, verified)
#pragma unroll
    for (int kk = 1; kk <= 9; ++kk) {
        const int k = 1 << kk;
#pragma unroll
        for (int jj = kk - 1; jj >= 0; --jj) {
            const int j = 1 << jj;
            if (j >= 8) {
                const int lj = j >> 3;
                const bool up = ((lane & (k >> 3)) == 0);
                const bool keep_min = (up == ((lane & lj) == 0));
#pragma unroll
                for (int s = 0; s < 8; ++s) {
                    const unsigned long long a  = v[s];
                    const unsigned long long vp = sx64(a, lj);
                    const bool lt = a < vp;
                    v[s] = (keep_min == lt) ? a : vp;
                }
            } else {
#pragma unroll
                for (int s = 0; s < 8; ++s) {
                    if ((s & j) == 0) {
                        const int p = s | j;
                        const bool up = ((((lane << 3) | s) & k) == 0);
                        const unsigned long long a = v[s], b = v[p];
                        const bool lt = a < b;
                        const bool do_swap = (lt != up);
                        v[s] = do_swap ? b : a;
                        v[p] = do_swap ? a : b;
                    }
                }
            }
        }
    }

    // v[s] holds sorted position lane*8+s -> source idx in low bits.
    vushort8 pk;
#pragma unroll
    for (int s = 0; s < 8; ++s)
        pk[s] = (unsigned short)(v[s] & 0xffffull);
    // lane-contiguous 16B stores: wave writes 1 KB contiguous per row.
    ((vushort8*)(perm + (size_t)row * NPK))[lane] = pk;
}

// ---------- Kernel B: pure gather + streaming stores ----------

__global__ __launch_bounds__(256, 8)
void gather_kernel(const float* __restrict__ z, const unsigned short* __restrict__ perm,
                   float* __restrict__ out) {
    __shared__ int srcs[NPK];                      // 2 KB

    const int t = threadIdx.x;
    const size_t rowoff = (size_t)blockIdx.x * DIM;
    const vfloat4* __restrict__ zin4 = (const vfloat4*)(z + rowoff);
    vfloat4* __restrict__ out4 = (vfloat4*)(out + rowoff);

    // perm row -> LDS (2 entries per thread, coalesced u32 loads)
    const unsigned int* __restrict__ pr =
        (const unsigned int*)(perm + (size_t)blockIdx.x * NPK);
    const unsigned int wp = pr[t];
    srcs[2 * t]     = (int)(wp & 0xffffu);
    srcs[2 * t + 1] = (int)(wp >> 16);
    __syncthreads();

    // 2048 float4 slots / 256 threads = 8 per thread, staged 4 at a time.
#pragma unroll
    for (int g = 0; g < 2; ++g) {
        int src[4];
        vfloat4 val[4];
#pragma unroll
        for (int i = 0; i < 4; ++i)
            src[i] = srcs[(t + 256 * (4 * g + i)) >> 2];   // broadcast reads
#pragma unroll
        for (int i = 0; i < 4; ++i) {
            const int o = t + 256 * (4 * g + i);
            val[i] = zin4[(src[i] << 2) | (o & 3)];        // L3-hot gather
        }
        __builtin_amdgcn_sched_barrier(0);                 // keep 4 loads in flight
#pragma unroll
        for (int i = 0; i < 4; ++i)
            __builtin_nontemporal_store(val[i], &out4[t + 256 * (4 * g + i)]);
    }
}

// ---------- Fallback: v7 single-kernel (ws too small) ----------

__global__ __launch_bounds__(512, 8)
void sort_latent_kernel(const float* __restrict__ z, float* __restrict__ out) {
    __shared__ __align__(16) unsigned long long keys[NPK];
    __shared__ int srcs[NPK];

    const int t = threadIdx.x;
    const size_t rowoff = (size_t)blockIdx.x * DIM;
    const float* __restrict__ zrow = z + rowoff;
    const vfloat4* __restrict__ zin4 = (const vfloat4*)zrow;
    vfloat4* __restrict__ out4 = (vfloat4*)(out + rowoff);

    unsigned int u = __float_as_uint(zrow[t * 16]);
    if (u == 0x80000000u) u = 0u;
    u = (u & 0x80000000u) ? ~u : (u | 0x80000000u);
    unsigned long long v = ((unsigned long long)u << 16) | (unsigned long long)t;

#pragma unroll
    for (int kk = 1; kk <= 9; ++kk) {
        const int k = 1 << kk;
#pragma unroll
        for (int jj = kk - 1; jj >= 0; --jj) {
            const int j = 1 << jj;
            unsigned long long vp;
            if (j < 64) {
                vp = shfl_xor_u64(v, j);
            } else {
                __syncthreads();
                keys[t] = v;
                __syncthreads();
                vp = keys[t ^ j];
            }
            const bool take_min = (((t & k) == 0) == ((t & j) == 0));
            const bool lt = (v < vp);
            v = (take_min == lt) ? v : vp;
        }
    }
    srcs[t] = (int)(v & 0xffffull);
    __syncthreads();

#pragma unroll
    for (int i = 0; i < 4; ++i) {
        const int o = t + 512 * i;
        const int src = srcs[o >> 2];
        __builtin_nontemporal_store(zin4[(src << 2) | (o & 3)], &out4[o]);
    }
}

extern "C" void kernel_launch(void* const* d_in, const int* in_sizes, int n_in,
                              void* d_out, int out_size, void* d_ws, size_t ws_size,
                              hipStream_t stream) {
    const float* z = (const float*)d_in[0];
    float* out = (float*)d_out;
    const int nrows = in_sizes[0] / DIM;           // 4096
    const size_t perm_bytes = (size_t)nrows * NPK * sizeof(unsigned short);

    if (d_ws != nullptr && ws_size >= perm_bytes) {
        unsigned short* perm = (unsigned short*)d_ws;
        sort_keys_kernel<<<nrows / 4, 256, 0, stream>>>(z, perm);
        gather_kernel<<<nrows, 256, 0, stream>>>(z, perm, out);
    } else {
        sort_latent_kernel<<<nrows, 512, 0, stream>>>(z, out);
    }
}